// Round 5
// baseline (1082.530 us; speedup 1.0000x reference)
//
#include <hip/hip_runtime.h>
#include <hip/hip_bf16.h>
#include <cstdint>
#include <cstddef>

using bf16 = __hip_bfloat16;
using short8 = __attribute__((ext_vector_type(8))) short;
using floatx4 = __attribute__((ext_vector_type(4))) float;

constexpr int D_IN = 1024;
constexpr int H_DIM = 4096;
constexpr int E_NUM = 8;
constexpr int NTOK = 8192;   // B*S
constexpr int NPAIR = NTOK * 2;
constexpr int MAXTILES = 144;  // sum ceil(cnt_e/128) <= 128+8; multiple of 8 (XCD map)

// ---------------- workspace layout (bytes) ----------------
constexpr size_t OFF_PTOK  = 1024;
constexpr size_t OFF_PPROB = 263168;
constexpr size_t OFF_SCHED = 525312;
constexpr size_t OFF_XBF   = 1048576;
constexpr size_t OFF_W2T   = OFF_XBF + (size_t)NTOK * D_IN * 2;
constexpr size_t OFF_HBUF  = OFF_W2T + (size_t)E_NUM * D_IN * H_DIM * 2;
constexpr size_t OFF_W1T   = OFF_HBUF + (size_t)NPAIR * H_DIM * 2;  // aliased by resbuf after gemm1

__device__ __forceinline__ void cp16(const bf16* g, bf16* s) {
  __builtin_amdgcn_global_load_lds(
      (const __attribute__((address_space(1))) unsigned int*)g,
      (__attribute__((address_space(3))) unsigned int*)s, 16, 0, 0);
}

// ---------- fp32 [K,N] -> bf16 [N,K] transposed convert, 64x64 tiles ----------
__global__ __launch_bounds__(256) void transpose_cvt(
    const float* __restrict__ in, bf16* __restrict__ out, int K, int N) {
  __shared__ float tile[64][65];
  const int e = blockIdx.z;
  const float* ip = in + (size_t)e * K * N + (size_t)(blockIdx.y * 64) * N + blockIdx.x * 64;
  bf16* op = out + (size_t)e * K * N + (size_t)(blockIdx.x * 64) * K + blockIdx.y * 64;
  const int tc = threadIdx.x & 15;   // col group (4 floats)
  const int tr = threadIdx.x >> 4;   // row 0..15
#pragma unroll
  for (int r = 0; r < 4; r++) {
    const float4 v = *(const float4*)&ip[(size_t)(tr + r * 16) * N + tc * 4];
    *(float4*)&tile[tr + r * 16][tc * 4] = v;
  }
  __syncthreads();
  const int kg = threadIdx.x & 7;    // k-group of 8
  const int nb = threadIdx.x >> 3;   // 0..31
#pragma unroll
  for (int r = 0; r < 2; r++) {
    const int n = nb + r * 32;
    union { short8 v; bf16 h[8]; } u;
#pragma unroll
    for (int j = 0; j < 8; j++) u.h[j] = __float2bfloat16(tile[kg * 8 + j][n]);
    *(short8*)&op[(size_t)n * K + kg * 8] = u.v;
  }
}

// ---------------- router: logits, softmax, top-2, x->bf16 ----------------
__global__ __launch_bounds__(256) void router_kernel(
    const float* __restrict__ x, const float* __restrict__ Wg,
    const float* __restrict__ bg, bf16* __restrict__ Xbf,
    int* __restrict__ counts, int* __restrict__ pairTok, float* __restrict__ pairProb) {
  const int lane = threadIdx.x & 63;
  const int n = blockIdx.x * 4 + (threadIdx.x >> 6);
  const float* xr = x + (size_t)n * D_IN;
  bf16* xbr = Xbf + (size_t)n * D_IN;
  float logit[E_NUM];
#pragma unroll
  for (int e = 0; e < E_NUM; e++) logit[e] = 0.f;
#pragma unroll
  for (int i = 0; i < 16; i++) {
    const int d = i * 64 + lane;
    const float xd = xr[d];
    xbr[d] = __float2bfloat16(xd);
    const float4* wr = (const float4*)(Wg + (size_t)d * E_NUM);
    const float4 w0 = wr[0], w1 = wr[1];
    logit[0] += xd * w0.x; logit[1] += xd * w0.y;
    logit[2] += xd * w0.z; logit[3] += xd * w0.w;
    logit[4] += xd * w1.x; logit[5] += xd * w1.y;
    logit[6] += xd * w1.z; logit[7] += xd * w1.w;
  }
#pragma unroll
  for (int e = 0; e < E_NUM; e++) {
#pragma unroll
    for (int off = 32; off >= 1; off >>= 1)
      logit[e] += __shfl_xor(logit[e], off, 64);
  }
  if (lane == 0) {
    float l[E_NUM], mx = -1e30f;
#pragma unroll
    for (int e = 0; e < E_NUM; e++) { l[e] = logit[e] + bg[e]; mx = fmaxf(mx, l[e]); }
    float ex[E_NUM], s = 0.f;
#pragma unroll
    for (int e = 0; e < E_NUM; e++) { ex[e] = expf(l[e] - mx); s += ex[e]; }
    int i0 = 0;
#pragma unroll
    for (int e = 1; e < E_NUM; e++) if (l[e] > l[i0]) i0 = e;
    int i1 = (i0 == 0) ? 1 : 0;
#pragma unroll
    for (int e = 0; e < E_NUM; e++) if (e != i0 && l[e] > l[i1]) i1 = e;
    const float inv = 1.f / s;
    int pos = atomicAdd(&counts[i0], 1);
    pairTok[i0 * NTOK + pos] = n;             // slot 0
    pairProb[i0 * NTOK + pos] = ex[i0] * inv;
    pos = atomicAdd(&counts[i1], 1);
    pairTok[i1 * NTOK + pos] = n | (1 << 15); // slot 1
    pairProb[i1 * NTOK + pos] = ex[i1] * inv;
  }
}

// ---------------- tile scheduler: exact (expert, m-tile) list ----------------
__global__ void sched_kernel(const int* __restrict__ counts, int* __restrict__ sched) {
  if (threadIdx.x == 0 && blockIdx.x == 0) {
    int* bases = sched;
    int* nTiles = sched + 8;
    int* tileMap = sched + 16;
    int base = 0, t = 0;
    for (int e = 0; e < E_NUM; e++) {
      bases[e] = base;
      const int nt = (counts[e] + 127) >> 7;
      for (int m = 0; m < nt; m++) tileMap[t++] = (e << 16) | m;
      base += counts[e];
    }
    *nTiles = t;
  }
}

// ---------------- grouped GEMM, 128x128 tile, BK=64 (2 panels/barrier) ------
// bid = nblk*MAXTILES + tix (MAXTILES%8==0) => XCD = tix%8: all n-blocks of an
// (expert,m-tile) share one XCD -> A tile L2-local. BK=64 halves the barrier
// count vs m97's BK=32: per iter 8 cp16, 1 barrier, 2x(8 ds_read + 16 MFMA).
// MODE 0: Hout[base+p][n] = gelu(Xbf[tok[p]] @ W1t[e]^T + b1[e])   (K=1024, NC=4096)
// MODE 1: Rout[tok*2+slot][n] = (Hbuf[base+p] @ W2t[e]^T + b2[e]) * prob
template <int MODE, int K, int NC>
__global__ __launch_bounds__(256) void gemm_kernel(
    const bf16* __restrict__ A, const bf16* __restrict__ Wt,
    const float* __restrict__ bias, const int* __restrict__ counts,
    const int* __restrict__ pairTok, const float* __restrict__ pairProb,
    const int* __restrict__ sched, bf16* __restrict__ Hout, float* __restrict__ Rout) {
  const int tix = blockIdx.x % MAXTILES;
  const int nblk = blockIdx.x / MAXTILES;
  if (tix >= sched[8]) return;
  const int packed = sched[16 + tix];
  const int e = packed >> 16;
  const int m0 = (packed & 0xFFFF) * 128;
  const int cnt = counts[e];
  const int base = sched[e];
  const int n0 = nblk * 128;

  // two 32-k panels each for A and B: 2 * 128*32 * 2B = 16 KB per operand
  __shared__ __align__(16) bf16 As[2 * 128 * 32];
  __shared__ __align__(16) bf16 Bs[2 * 128 * 32];

  const int t = threadIdx.x;
  const int lane = t & 63;
  const int wave = t >> 6;
  const int wmq = wave >> 1, wnq = wave & 1;  // 2x2 wave grid, 64x64 each
  const int fr = lane & 15;
  const int kg = (lane >> 4) * 8;

  const bf16* aSrc[2];
  const bf16* bSrc[2];
#pragma unroll
  for (int i = 0; i < 2; i++) {
    const int lin = i * 256 + t;   // 16B units across a 128x32 panel
    const int r = lin >> 2;
    const int c8 = (lin & 3) * 8;
    int p = m0 + r;
    if (p > cnt - 1) p = cnt - 1;  // clamp: rows past count read a valid row
    if (MODE == 0) {
      const int tok = pairTok[e * NTOK + p] & 0x1FFF;
      aSrc[i] = A + (size_t)tok * K + c8;
    } else {
      aSrc[i] = A + (size_t)(base + p) * K + c8;
    }
    bSrc[i] = Wt + ((size_t)e * NC + n0 + r) * K + c8;
  }

  floatx4 acc[4][4];
#pragma unroll
  for (int ti = 0; ti < 4; ti++)
#pragma unroll
    for (int tj = 0; tj < 4; tj++)
      acc[ti][tj] = {0.f, 0.f, 0.f, 0.f};

  for (int k0 = 0; k0 < K; k0 += 64) {
#pragma unroll
    for (int pnl = 0; pnl < 2; pnl++) {
#pragma unroll
      for (int i = 0; i < 2; i++) {
        const int lin = i * 256 + t;
        cp16(aSrc[i] + k0 + pnl * 32, &As[pnl * 4096 + lin * 8]);
        cp16(bSrc[i] + k0 + pnl * 32, &Bs[pnl * 4096 + lin * 8]);
      }
    }
    __syncthreads();
#pragma unroll
    for (int pnl = 0; pnl < 2; pnl++) {
      short8 a[4], b[4];
#pragma unroll
      for (int ti = 0; ti < 4; ti++)
        a[ti] = *(const short8*)&As[pnl * 4096 + (wmq * 64 + ti * 16 + fr) * 32 + kg];
#pragma unroll
      for (int tj = 0; tj < 4; tj++)
        b[tj] = *(const short8*)&Bs[pnl * 4096 + (wnq * 64 + tj * 16 + fr) * 32 + kg];
#pragma unroll
      for (int ti = 0; ti < 4; ti++)
#pragma unroll
        for (int tj = 0; tj < 4; tj++)
          acc[ti][tj] = __builtin_amdgcn_mfma_f32_16x16x32_bf16(a[ti], b[tj], acc[ti][tj], 0, 0, 0);
    }
    __syncthreads();
  }

  float bv[4];
#pragma unroll
  for (int tj = 0; tj < 4; tj++)
    bv[tj] = bias[(size_t)e * NC + n0 + wnq * 64 + tj * 16 + fr];

#pragma unroll
  for (int ti = 0; ti < 4; ti++) {
    const int rb = wmq * 64 + ti * 16 + (lane >> 4) * 4;
#pragma unroll
    for (int i = 0; i < 4; i++) {
      const int p = m0 + rb + i;
      if (p < cnt) {
        if (MODE == 0) {
          bf16* orow = Hout + (size_t)(base + p) * NC + n0 + wnq * 64 + fr;
#pragma unroll
          for (int tj = 0; tj < 4; tj++) {
            const float h = acc[ti][tj][i] + bv[tj];
            const float g = 0.5f * h * (1.f + erff(h * 0.70710678118f));
            orow[tj * 16] = __float2bfloat16(g);
          }
        } else {
          const int pt = pairTok[e * NTOK + p];
          const float pr = pairProb[e * NTOK + p];
          const int tok = pt & 0x1FFF, slot = (pt >> 15) & 1;
          float* orow = Rout + ((size_t)(tok * 2 + slot)) * NC + n0 + wnq * 64 + fr;
#pragma unroll
          for (int tj = 0; tj < 4; tj++)
            orow[tj * 16] = (acc[ti][tj][i] + bv[tj]) * pr;
        }
      }
    }
  }
}

// ---------------- combine: out[n] = res[n][0] + res[n][1] ----------------
__global__ __launch_bounds__(256) void combine_kernel(
    const float4* __restrict__ r, float4* __restrict__ o) {
  const int j = blockIdx.x * 256 + threadIdx.x;  // one float4 of out
  const int n = j >> 8, c = j & 255;             // 256 float4 per row of D=1024
  const float4 a = r[(size_t)(n * 2) * 256 + c];
  const float4 b = r[(size_t)(n * 2 + 1) * 256 + c];
  o[j] = make_float4(a.x + b.x, a.y + b.y, a.z + b.z, a.w + b.w);
}

extern "C" void kernel_launch(void* const* d_in, const int* in_sizes, int n_in,
                              void* d_out, int out_size, void* d_ws, size_t ws_size,
                              hipStream_t stream) {
  const float* x  = (const float*)d_in[0];
  const float* Wg = (const float*)d_in[1];
  const float* bg = (const float*)d_in[2];
  const float* W1 = (const float*)d_in[3];
  const float* b1 = (const float*)d_in[4];
  const float* W2 = (const float*)d_in[5];
  const float* b2 = (const float*)d_in[6];
  float* out = (float*)d_out;
  char* ws = (char*)d_ws;

  int*   counts   = (int*)ws;
  int*   pairTok  = (int*)(ws + OFF_PTOK);
  float* pairProb = (float*)(ws + OFF_PPROB);
  int*   sched    = (int*)(ws + OFF_SCHED);
  bf16*  Xbf      = (bf16*)(ws + OFF_XBF);
  bf16*  W2t      = (bf16*)(ws + OFF_W2T);
  bf16*  Hbuf     = (bf16*)(ws + OFF_HBUF);
  bf16*  W1t      = (bf16*)(ws + OFF_W1T);
  float* resbuf   = (float*)W1t;  // alias: W1t dead after gemm1

  hipMemsetAsync(counts, 0, 64, stream);
  // W1 [E][1024][4096] -> W1t [E][4096][1024]
  transpose_cvt<<<dim3(H_DIM / 64, D_IN / 64, E_NUM), 256, 0, stream>>>(W1, W1t, D_IN, H_DIM);
  // W2 [E][4096][1024] -> W2t [E][1024][4096]
  transpose_cvt<<<dim3(D_IN / 64, H_DIM / 64, E_NUM), 256, 0, stream>>>(W2, W2t, H_DIM, D_IN);
  router_kernel<<<NTOK / 4, 256, 0, stream>>>(x, Wg, bg, Xbf, counts, pairTok, pairProb);
  sched_kernel<<<1, 64, 0, stream>>>(counts, sched);
  gemm_kernel<0, D_IN, H_DIM><<<32 * MAXTILES, 256, 0, stream>>>(
      Xbf, W1t, b1, counts, pairTok, pairProb, sched, Hbuf, resbuf);
  gemm_kernel<1, H_DIM, D_IN><<<8 * MAXTILES, 256, 0, stream>>>(
      Hbuf, W2t, b2, counts, pairTok, pairProb, sched, Hbuf, resbuf);
  combine_kernel<<<(NTOK * D_IN / 4) / 256, 256, 0, stream>>>((const float4*)resbuf, (float4*)out);
}

// Round 6
// 843.206 us; speedup vs baseline: 1.2838x; 1.2838x over previous
//
#include <hip/hip_runtime.h>
#include <hip/hip_bf16.h>
#include <cstdint>
#include <cstddef>

using bf16 = __hip_bfloat16;
using short8 = __attribute__((ext_vector_type(8))) short;
using floatx4 = __attribute__((ext_vector_type(4))) float;

constexpr int D_IN = 1024;
constexpr int H_DIM = 4096;
constexpr int E_NUM = 8;
constexpr int NTOK = 8192;   // B*S
constexpr int NPAIR = NTOK * 2;
constexpr int MAXTILES = 144;  // sum ceil(cnt_e/128) <= 128+8; multiple of 8 (XCD map)

// ---------------- workspace layout (bytes) ----------------
constexpr size_t OFF_PTOK  = 1024;
constexpr size_t OFF_PPROB = 263168;
constexpr size_t OFF_SCHED = 525312;
constexpr size_t OFF_XBF   = 1048576;
constexpr size_t OFF_W2T   = OFF_XBF + (size_t)NTOK * D_IN * 2;
constexpr size_t OFF_HBUF  = OFF_W2T + (size_t)E_NUM * D_IN * H_DIM * 2;
constexpr size_t OFF_W1T   = OFF_HBUF + (size_t)NPAIR * H_DIM * 2;  // aliased by resbuf after gemm1

__device__ __forceinline__ void cp16(const bf16* g, bf16* s) {
  __builtin_amdgcn_global_load_lds(
      (const __attribute__((address_space(1))) unsigned int*)g,
      (__attribute__((address_space(3))) unsigned int*)s, 16, 0, 0);
}

// ---------- fp32 [K,N] -> bf16 [N,K] transposed convert, 64x64 tiles ----------
__global__ __launch_bounds__(256) void transpose_cvt(
    const float* __restrict__ in, bf16* __restrict__ out, int K, int N) {
  __shared__ float tile[64][65];
  const int e = blockIdx.z;
  const float* ip = in + (size_t)e * K * N + (size_t)(blockIdx.y * 64) * N + blockIdx.x * 64;
  bf16* op = out + (size_t)e * K * N + (size_t)(blockIdx.x * 64) * K + blockIdx.y * 64;
  const int tc = threadIdx.x & 15;   // col group (4 floats)
  const int tr = threadIdx.x >> 4;   // row 0..15
#pragma unroll
  for (int r = 0; r < 4; r++) {
    const float4 v = *(const float4*)&ip[(size_t)(tr + r * 16) * N + tc * 4];
    *(float4*)&tile[tr + r * 16][tc * 4] = v;
  }
  __syncthreads();
  const int kg = threadIdx.x & 7;    // k-group of 8
  const int nb = threadIdx.x >> 3;   // 0..31
#pragma unroll
  for (int r = 0; r < 2; r++) {
    const int n = nb + r * 32;
    union { short8 v; bf16 h[8]; } u;
#pragma unroll
    for (int j = 0; j < 8; j++) u.h[j] = __float2bfloat16(tile[kg * 8 + j][n]);
    *(short8*)&op[(size_t)n * K + kg * 8] = u.v;
  }
}

// ------- router: logits, softmax, top-2, x->bf16; HIERARCHICAL atomics ------
// 32 tokens/block. LDS atomics count locally; ONE global atomicAdd per expert
// per block (2048 total vs 16384 contended before); scatter with local offset.
__global__ __launch_bounds__(256) void router_kernel(
    const float* __restrict__ x, const float* __restrict__ Wg,
    const float* __restrict__ bg, bf16* __restrict__ Xbf,
    int* __restrict__ counts, int* __restrict__ pairTok, float* __restrict__ pairProb) {
  __shared__ int lcnt[E_NUM];
  __shared__ int sBase[E_NUM];
  __shared__ int sE0[32], sL0[32], sE1[32], sL1[32];
  __shared__ float sP0[32], sP1[32];
  const int lane = threadIdx.x & 63;
  const int wave = threadIdx.x >> 6;
  if (threadIdx.x < E_NUM) lcnt[threadIdx.x] = 0;
  __syncthreads();

  for (int tk = 0; tk < 8; tk++) {
    const int li = wave * 8 + tk;
    const int n = blockIdx.x * 32 + li;
    const float* xr = x + (size_t)n * D_IN;
    bf16* xbr = Xbf + (size_t)n * D_IN;
    float logit[E_NUM];
#pragma unroll
    for (int e = 0; e < E_NUM; e++) logit[e] = 0.f;
#pragma unroll
    for (int i = 0; i < 16; i++) {
      const int d = i * 64 + lane;
      const float xd = xr[d];
      xbr[d] = __float2bfloat16(xd);
      const float4* wr = (const float4*)(Wg + (size_t)d * E_NUM);
      const float4 w0 = wr[0], w1 = wr[1];
      logit[0] += xd * w0.x; logit[1] += xd * w0.y;
      logit[2] += xd * w0.z; logit[3] += xd * w0.w;
      logit[4] += xd * w1.x; logit[5] += xd * w1.y;
      logit[6] += xd * w1.z; logit[7] += xd * w1.w;
    }
#pragma unroll
    for (int e = 0; e < E_NUM; e++) {
#pragma unroll
      for (int off = 32; off >= 1; off >>= 1)
        logit[e] += __shfl_xor(logit[e], off, 64);
    }
    if (lane == 0) {
      float l[E_NUM], mx = -1e30f;
#pragma unroll
      for (int e = 0; e < E_NUM; e++) { l[e] = logit[e] + bg[e]; mx = fmaxf(mx, l[e]); }
      float ex[E_NUM], s = 0.f;
#pragma unroll
      for (int e = 0; e < E_NUM; e++) { ex[e] = expf(l[e] - mx); s += ex[e]; }
      int i0 = 0;
#pragma unroll
      for (int e = 1; e < E_NUM; e++) if (l[e] > l[i0]) i0 = e;
      int i1 = (i0 == 0) ? 1 : 0;
#pragma unroll
      for (int e = 0; e < E_NUM; e++) if (e != i0 && l[e] > l[i1]) i1 = e;
      const float inv = 1.f / s;
      sE0[li] = i0; sL0[li] = atomicAdd(&lcnt[i0], 1); sP0[li] = ex[i0] * inv;
      sE1[li] = i1; sL1[li] = atomicAdd(&lcnt[i1], 1); sP1[li] = ex[i1] * inv;
    }
  }
  __syncthreads();
  if (threadIdx.x < E_NUM)
    sBase[threadIdx.x] = atomicAdd(&counts[threadIdx.x], lcnt[threadIdx.x]);
  __syncthreads();
  if (threadIdx.x < 32) {
    const int li = threadIdx.x;
    const int n = blockIdx.x * 32 + li;
    const int e0 = sE0[li], p0 = sBase[e0] + sL0[li];
    pairTok[e0 * NTOK + p0] = n;               // slot 0
    pairProb[e0 * NTOK + p0] = sP0[li];
    const int e1 = sE1[li], p1 = sBase[e1] + sL1[li];
    pairTok[e1 * NTOK + p1] = n | (1 << 15);   // slot 1
    pairProb[e1 * NTOK + p1] = sP1[li];
  }
}

// ---------------- tile scheduler: exact (expert, m-tile) list ----------------
__global__ void sched_kernel(const int* __restrict__ counts, int* __restrict__ sched) {
  if (threadIdx.x == 0 && blockIdx.x == 0) {
    int* bases = sched;
    int* nTiles = sched + 8;
    int* tileMap = sched + 16;
    int base = 0, t = 0;
    for (int e = 0; e < E_NUM; e++) {
      bases[e] = base;
      const int nt = (counts[e] + 127) >> 7;
      for (int m = 0; m < nt; m++) tileMap[t++] = (e << 16) | m;
      base += counts[e];
    }
    *nTiles = t;
  }
}

// ---------------- grouped GEMM, 128x128x32, 16x16x32 bf16 MFMA --------------
// bid = nblk*MAXTILES + tix (MAXTILES%8==0) => XCD = tix%8: all n-blocks of an
// (expert,m-tile) share one XCD -> A tile fetched once into that XCD's L2.
// MODE 0: Hout[base+p][n] = gelu(Xbf[tok[p]] @ W1t[e]^T + b1[e])   (K=1024, NC=4096)
// MODE 1: Rout[tok*2+slot][n] = (Hbuf[base+p] @ W2t[e]^T + b2[e]) * prob
template <int MODE, int K, int NC>
__global__ __launch_bounds__(256) void gemm_kernel(
    const bf16* __restrict__ A, const bf16* __restrict__ Wt,
    const float* __restrict__ bias, const int* __restrict__ counts,
    const int* __restrict__ pairTok, const float* __restrict__ pairProb,
    const int* __restrict__ sched, bf16* __restrict__ Hout, float* __restrict__ Rout) {
  const int tix = blockIdx.x % MAXTILES;
  const int nblk = blockIdx.x / MAXTILES;
  if (tix >= sched[8]) return;
  const int packed = sched[16 + tix];
  const int e = packed >> 16;
  const int m0 = (packed & 0xFFFF) * 128;
  const int cnt = counts[e];
  const int base = sched[e];
  const int n0 = nblk * 128;

  __shared__ __align__(16) bf16 As[128 * 32];
  __shared__ __align__(16) bf16 Bs[128 * 32];

  const int t = threadIdx.x;
  const int lane = t & 63;
  const int wave = t >> 6;
  const int wmq = wave >> 1, wnq = wave & 1;  // 2x2 wave grid, 64x64 each
  const int fr = lane & 15;
  const int kg = (lane >> 4) * 8;

  const bf16* aSrc[2];
  const bf16* bSrc[2];
#pragma unroll
  for (int i = 0; i < 2; i++) {
    const int lin = i * 256 + t;   // 16B units across the tile
    const int r = lin >> 2;
    const int c8 = (lin & 3) * 8;
    int p = m0 + r;
    if (p > cnt - 1) p = cnt - 1;  // clamp: rows past count read a valid row
    if (MODE == 0) {
      const int tok = pairTok[e * NTOK + p] & 0x1FFF;
      aSrc[i] = A + (size_t)tok * K + c8;
    } else {
      aSrc[i] = A + (size_t)(base + p) * K + c8;
    }
    bSrc[i] = Wt + ((size_t)e * NC + n0 + r) * K + c8;
  }

  floatx4 acc[4][4];
#pragma unroll
  for (int ti = 0; ti < 4; ti++)
#pragma unroll
    for (int tj = 0; tj < 4; tj++)
      acc[ti][tj] = {0.f, 0.f, 0.f, 0.f};

  for (int k0 = 0; k0 < K; k0 += 32) {
#pragma unroll
    for (int i = 0; i < 2; i++) {
      cp16(aSrc[i] + k0, &As[(size_t)(i * 256 + t) * 8]);
      cp16(bSrc[i] + k0, &Bs[(size_t)(i * 256 + t) * 8]);
    }
    __syncthreads();
    short8 a[4], b[4];
#pragma unroll
    for (int ti = 0; ti < 4; ti++)
      a[ti] = *(const short8*)&As[(wmq * 64 + ti * 16 + fr) * 32 + kg];
#pragma unroll
    for (int tj = 0; tj < 4; tj++)
      b[tj] = *(const short8*)&Bs[(wnq * 64 + tj * 16 + fr) * 32 + kg];
#pragma unroll
    for (int ti = 0; ti < 4; ti++)
#pragma unroll
      for (int tj = 0; tj < 4; tj++)
        acc[ti][tj] = __builtin_amdgcn_mfma_f32_16x16x32_bf16(a[ti], b[tj], acc[ti][tj], 0, 0, 0);
    __syncthreads();
  }

  float bv[4];
#pragma unroll
  for (int tj = 0; tj < 4; tj++)
    bv[tj] = bias[(size_t)e * NC + n0 + wnq * 64 + tj * 16 + fr];

#pragma unroll
  for (int ti = 0; ti < 4; ti++) {
    const int rb = wmq * 64 + ti * 16 + (lane >> 4) * 4;
#pragma unroll
    for (int i = 0; i < 4; i++) {
      const int p = m0 + rb + i;
      if (p < cnt) {
        if (MODE == 0) {
          bf16* orow = Hout + (size_t)(base + p) * NC + n0 + wnq * 64 + fr;
#pragma unroll
          for (int tj = 0; tj < 4; tj++) {
            const float h = acc[ti][tj][i] + bv[tj];
            const float g = 0.5f * h * (1.f + erff(h * 0.70710678118f));
            orow[tj * 16] = __float2bfloat16(g);
          }
        } else {
          const int pt = pairTok[e * NTOK + p];
          const float pr = pairProb[e * NTOK + p];
          const int tok = pt & 0x1FFF, slot = (pt >> 15) & 1;
          float* orow = Rout + ((size_t)(tok * 2 + slot)) * NC + n0 + wnq * 64 + fr;
#pragma unroll
          for (int tj = 0; tj < 4; tj++)
            orow[tj * 16] = (acc[ti][tj][i] + bv[tj]) * pr;
        }
      }
    }
  }
}

// ---------------- combine: out[n] = res[n][0] + res[n][1] ----------------
__global__ __launch_bounds__(256) void combine_kernel(
    const float4* __restrict__ r, float4* __restrict__ o) {
  const int j = blockIdx.x * 256 + threadIdx.x;  // one float4 of out
  const int n = j >> 8, c = j & 255;             // 256 float4 per row of D=1024
  const float4 a = r[(size_t)(n * 2) * 256 + c];
  const float4 b = r[(size_t)(n * 2 + 1) * 256 + c];
  o[j] = make_float4(a.x + b.x, a.y + b.y, a.z + b.z, a.w + b.w);
}

extern "C" void kernel_launch(void* const* d_in, const int* in_sizes, int n_in,
                              void* d_out, int out_size, void* d_ws, size_t ws_size,
                              hipStream_t stream) {
  const float* x  = (const float*)d_in[0];
  const float* Wg = (const float*)d_in[1];
  const float* bg = (const float*)d_in[2];
  const float* W1 = (const float*)d_in[3];
  const float* b1 = (const float*)d_in[4];
  const float* W2 = (const float*)d_in[5];
  const float* b2 = (const float*)d_in[6];
  float* out = (float*)d_out;
  char* ws = (char*)d_ws;

  int*   counts   = (int*)ws;
  int*   pairTok  = (int*)(ws + OFF_PTOK);
  float* pairProb = (float*)(ws + OFF_PPROB);
  int*   sched    = (int*)(ws + OFF_SCHED);
  bf16*  Xbf      = (bf16*)(ws + OFF_XBF);
  bf16*  W2t      = (bf16*)(ws + OFF_W2T);
  bf16*  Hbuf     = (bf16*)(ws + OFF_HBUF);
  bf16*  W1t      = (bf16*)(ws + OFF_W1T);
  float* resbuf   = (float*)W1t;  // alias: W1t dead after gemm1

  hipMemsetAsync(counts, 0, 64, stream);
  // W1 [E][1024][4096] -> W1t [E][4096][1024]
  transpose_cvt<<<dim3(H_DIM / 64, D_IN / 64, E_NUM), 256, 0, stream>>>(W1, W1t, D_IN, H_DIM);
  // W2 [E][4096][1024] -> W2t [E][1024][4096]
  transpose_cvt<<<dim3(D_IN / 64, H_DIM / 64, E_NUM), 256, 0, stream>>>(W2, W2t, H_DIM, D_IN);
  router_kernel<<<NTOK / 32, 256, 0, stream>>>(x, Wg, bg, Xbf, counts, pairTok, pairProb);
  sched_kernel<<<1, 64, 0, stream>>>(counts, sched);
  gemm_kernel<0, D_IN, H_DIM><<<32 * MAXTILES, 256, 0, stream>>>(
      Xbf, W1t, b1, counts, pairTok, pairProb, sched, Hbuf, resbuf);
  gemm_kernel<1, H_DIM, D_IN><<<8 * MAXTILES, 256, 0, stream>>>(
      Hbuf, W2t, b2, counts, pairTok, pairProb, sched, Hbuf, resbuf);
  combine_kernel<<<(NTOK * D_IN / 4) / 256, 256, 0, stream>>>((const float4*)resbuf, (float4*)out);
}